// Round 1
// baseline (1051.765 us; speedup 1.0000x reference)
//
#include <hip/hip_runtime.h>
#include <hip/hip_bf16.h>

#define N_PTS   131072
#define N_FEATS 1000
#define FDIM    64
#define HID     128
#define BLOCK   256
#define PI_F    3.14159265358979f

// Fully fused: softmax-weighted feature interpolation + PE + 5-layer MLP.
// 1 point per thread. All weight/location/feature reads are wave-uniform
// (uniform indices on restrict pointers) -> scalar loads, no LDS broadcast.
// LDS is used ONLY as per-thread activation scratch (own column; no barriers).
__global__ __launch_bounds__(BLOCK, 2)
void afvsrn_fused(const float* __restrict__ x,
                  const float* __restrict__ locs,
                  const float* __restrict__ fv,
                  const float* __restrict__ W0, const float* __restrict__ b0,
                  const float* __restrict__ W1, const float* __restrict__ b1,
                  const float* __restrict__ W2, const float* __restrict__ b2,
                  const float* __restrict__ W3, const float* __restrict__ b3,
                  const float* __restrict__ W4, const float* __restrict__ b4,
                  float* __restrict__ out)
{
    // 128 * 256 * 2B = 64 KB. Each thread uses only column [.][tid]:
    // consecutive-lane u16 -> 2 lanes per dword-bank -> conflict-free.
    __shared__ __hip_bfloat16 act[HID][BLOCK];

    const int tid = threadIdx.x;
    const int pt  = blockIdx.x * BLOCK + tid;
    if (pt >= N_PTS) return;

    const float x0 = x[pt*3+0], x1 = x[pt*3+1], x2 = x[pt*3+2];

    // ---------------- phase A: softmax(1/dist) weighted features ----------------
    // pass 1: running max of inv_d (needed: inv_d can be ~1e6 -> exp overflow)
    float m = -1e30f;
    for (int f = 0; f < N_FEATS; ++f) {
        float dx = x0 - locs[f*3+0];
        float dy = x1 - locs[f*3+1];
        float dz = x2 - locs[f*3+2];
        float d2 = dx*dx + dy*dy + dz*dz;
        float inv = 1.0f / (sqrtf(d2) + 1e-6f);
        m = fmaxf(m, inv);
    }

    // pass 2: l = sum exp(inv-m); acc = sum exp(inv-m) * fv[f]
    float acc[FDIM];
    #pragma unroll
    for (int j = 0; j < FDIM; ++j) acc[j] = 0.0f;
    float lsum = 0.0f;

    for (int f = 0; f < N_FEATS; ++f) {
        float dx = x0 - locs[f*3+0];
        float dy = x1 - locs[f*3+1];
        float dz = x2 - locs[f*3+2];
        float d2 = dx*dx + dy*dy + dz*dz;
        float inv = 1.0f / (sqrtf(d2) + 1e-6f);
        float p = __expf(inv - m);
        lsum += p;
        const float* __restrict__ fvf = fv + f*FDIM;   // wave-uniform row
        #pragma unroll
        for (int j = 0; j < FDIM; ++j)
            acc[j] = fmaf(p, fvf[j], acc[j]);
    }

    // ---------------- phase B: positional encoding + MLP ----------------
    float in100[100];
    #pragma unroll
    for (int d = 0; d < 3; ++d) {
        const float xv = (d == 0) ? x0 : (d == 1) ? x1 : x2;
        #pragma unroll
        for (int l = 0; l < 6; ++l) {
            float a = xv * (PI_F * (float)(1 << l));
            in100[d*12 + l]     = __sinf(a);
            in100[d*12 + 6 + l] = __cosf(a);
        }
    }
    const float linv = 1.0f / lsum;
    #pragma unroll
    for (int j = 0; j < FDIM; ++j) in100[36 + j] = acc[j] * linv;

    // layer 0: 100 -> 128, snake_alt, store to LDS scratch (bf16)
    for (int jc = 0; jc < HID/16; ++jc) {       // runtime loop keeps I$ small
        float a16[16];
        #pragma unroll
        for (int jj = 0; jj < 16; ++jj) a16[jj] = b0[jc*16 + jj];
        #pragma unroll
        for (int k = 0; k < 100; ++k) {
            const float av = in100[k];
            #pragma unroll
            for (int jj = 0; jj < 16; ++jj)
                a16[jj] = fmaf(av, W0[(jc*16 + jj)*100 + k], a16[jj]);
        }
        #pragma unroll
        for (int jj = 0; jj < 16; ++jj) {
            float h = a16[jj];
            float s = __sinf(h);
            h = 0.5f*h + s*s;                    // SnakeAlt
            act[jc*16 + jj][tid] = __float2bfloat16(h);
        }
    }

    // layers 1..3: 128 -> 128 (same code body, runtime layer loop)
    for (int L = 0; L < 3; ++L) {
        const float* __restrict__ W = (L == 0) ? W1 : (L == 1) ? W2 : W3;
        const float* __restrict__ B = (L == 0) ? b1 : (L == 1) ? b2 : b3;

        float in128[HID];
        #pragma unroll
        for (int k = 0; k < HID; ++k)
            in128[k] = __bfloat162float(act[k][tid]);   // own column only

        for (int jc = 0; jc < HID/16; ++jc) {
            float a16[16];
            #pragma unroll
            for (int jj = 0; jj < 16; ++jj) a16[jj] = B[jc*16 + jj];
            #pragma unroll
            for (int k = 0; k < HID; ++k) {
                const float av = in128[k];
                #pragma unroll
                for (int jj = 0; jj < 16; ++jj)
                    a16[jj] = fmaf(av, W[(jc*16 + jj)*HID + k], a16[jj]);
            }
            #pragma unroll
            for (int jj = 0; jj < 16; ++jj) {
                float h = a16[jj];
                float s = __sinf(h);
                h = 0.5f*h + s*s;
                act[jc*16 + jj][tid] = __float2bfloat16(h);
            }
        }
    }

    // layer 4: 128 -> 1
    float o = b4[0];
    #pragma unroll
    for (int k = 0; k < HID; ++k)
        o = fmaf(__bfloat162float(act[k][tid]), W4[k], o);
    out[pt] = o;
}

extern "C" void kernel_launch(void* const* d_in, const int* in_sizes, int n_in,
                              void* d_out, int out_size, void* d_ws, size_t ws_size,
                              hipStream_t stream)
{
    const float* x  = (const float*)d_in[0];
    const float* lc = (const float*)d_in[1];
    const float* fv = (const float*)d_in[2];
    const float* W0 = (const float*)d_in[3];
    const float* b0 = (const float*)d_in[4];
    const float* W1 = (const float*)d_in[5];
    const float* b1 = (const float*)d_in[6];
    const float* W2 = (const float*)d_in[7];
    const float* b2 = (const float*)d_in[8];
    const float* W3 = (const float*)d_in[9];
    const float* b3 = (const float*)d_in[10];
    const float* W4 = (const float*)d_in[11];
    const float* b4 = (const float*)d_in[12];

    afvsrn_fused<<<dim3(N_PTS/BLOCK), dim3(BLOCK), 0, stream>>>(
        x, lc, fv, W0, b0, W1, b1, W2, b2, W3, b3, W4, b4, (float*)d_out);
}

// Round 2
// 280.235 us; speedup vs baseline: 3.7531x; 3.7531x over previous
//
#include <hip/hip_runtime.h>

#define N_PTS   131072
#define N_FEATS 1000
#define FDIM    64
#define HID     128
#define NCHUNK  32          // 32 K-chunks of 32 features (padded 1000 -> 1024)
#define PI_F    3.14159265358979f

typedef short  short8  __attribute__((ext_vector_type(8)));   // bf16 A/B frag (4 VGPRs)
typedef float  floatx4 __attribute__((ext_vector_type(4)));   // C/D frag

// ---- bf16 helpers (self-contained, RNE) ----
__device__ __forceinline__ unsigned short f2bf(float f) {
    unsigned int u = __float_as_uint(f);
    u = (u + 0x7FFFu + ((u >> 16) & 1u)) >> 16;
    return (unsigned short)u;
}
__device__ __forceinline__ float bf2f(unsigned short h) {
    return __uint_as_float(((unsigned int)h) << 16);
}

// ---------------- prep kernels: repack inputs into d_ws every launch ----------------
// locs4: [1024][4] fp32 (xyz + pad), zero-padded past 1000
__global__ void prep_locs4(const float* __restrict__ locs, float* __restrict__ locs4) {
    int t = blockIdx.x * 256 + threadIdx.x;
    if (t >= 1024) return;
    float a = 0.f, b = 0.f, c = 0.f;
    if (t < N_FEATS) { a = locs[t*3+0]; b = locs[t*3+1]; c = locs[t*3+2]; }
    locs4[t*4+0] = a; locs4[t*4+1] = b; locs4[t*4+2] = c; locs4[t*4+3] = 0.f;
}

// fvB: B-fragment-ordered bf16 of fv: [cq=chunk*4+quad][n=0..63][j=0..7]
__global__ void prep_fvB(const float* __restrict__ fv, unsigned short* __restrict__ fvB) {
    int i = blockIdx.x * 256 + threadIdx.x;          // 65536 = 128*64*8
    if (i >= 128*64*8) return;
    int j = i & 7, n = (i >> 3) & 63, cq = i >> 9;
    int f = (cq >> 2) * 32 + (cq & 3) * 8 + j;       // feature index
    float v = (f < N_FEATS) ? fv[f*FDIM + n] : 0.f;
    fvB[i] = f2bf(v);
}

// WB[L]: B-fragment-ordered bf16 of W_L (torch [out,in]): [cq=c*4+q][n=0..127][j=0..7]
// layer 0 K=100 zero-padded to 128.
__global__ void prep_WB(const float* __restrict__ W0, const float* __restrict__ W1,
                        const float* __restrict__ W2, const float* __restrict__ W3,
                        unsigned short* __restrict__ WB) {
    int i = blockIdx.x * 256 + threadIdx.x;          // 4 layers * 16384
    if (i >= 4*16384) return;
    int L = i >> 14, r = i & 16383;
    int j = r & 7, n = (r >> 3) & 127, cq = r >> 10;
    int k = (cq >> 2) * 32 + (cq & 3) * 8 + j;
    const float* W = (L == 0) ? W0 : (L == 1) ? W1 : (L == 2) ? W2 : W3;
    int Kin = (L == 0) ? 100 : 128;
    float v = (k < Kin) ? W[n*Kin + k] : 0.f;
    WB[i] = f2bf(v);
}

// ---------------- main fused kernel ----------------
// Block = 256 threads = 4 waves, 16 points per wave (64/block). No __syncthreads:
// LDS activation rows are wave-private; weights come pre-fragmented from d_ws.
__global__ __launch_bounds__(256)
void afvsrn_mfma(const float* __restrict__ x,
                 const float* __restrict__ locs4,      // ws
                 const unsigned short* __restrict__ fvB, // ws
                 const unsigned short* __restrict__ WB,  // ws (4 layers)
                 const float* __restrict__ b0, const float* __restrict__ b1,
                 const float* __restrict__ b2, const float* __restrict__ b3,
                 const float* __restrict__ W4, const float* __restrict__ b4,
                 float* __restrict__ out)
{
    __shared__ unsigned short act[64 * 136];   // [64 pts][128 + 8 pad] bf16, 17.4 KB

    const int lane = threadIdx.x & 63;
    const int wv   = threadIdx.x >> 6;         // wave 0..3
    const int ptl  = lane & 15;                // A-frag row m / C-frag col n
    const int quad = lane >> 4;                // A/B-frag k-group, C-frag row-group
    const int ptbase = blockIdx.x * 64 + wv * 16;

    const float x0 = x[(ptbase + ptl)*3 + 0];
    const float x1 = x[(ptbase + ptl)*3 + 1];
    const float x2 = x[(ptbase + ptl)*3 + 2];

    const floatx4* lp4 = (const floatx4*)locs4;

    // ---------- pass 1: m = max_f 1/(sqrt(d2)+1e-6) ----------
    float m = -1e30f;
    for (int c = 0; c < NCHUNK; ++c) {
        const floatx4* lp = lp4 + c*32 + quad*8;
        const bool valid = (c < NCHUNK-1) || (quad == 0);   // f<1000
        #pragma unroll
        for (int j = 0; j < 8; ++j) {
            floatx4 L = lp[j];
            float dx = x0 - L[0], dy = x1 - L[1], dz = x2 - L[2];
            float d2 = fmaf(dx, dx, fmaf(dy, dy, dz*dz));
            d2 = fmaxf(d2, 1e-24f);
            float rs = __builtin_amdgcn_rsqf(d2);
            float inv = __builtin_amdgcn_rcpf(fmaf(d2, rs, 1e-6f)); // 1/(sqrt+1e-6)
            if (valid) m = fmaxf(m, inv);
        }
    }
    m = fmaxf(m, __shfl_xor(m, 16));
    m = fmaxf(m, __shfl_xor(m, 32));          // all 4 quads of a pt agree

    // ---------- pass 2: p = exp(inv-m) straight into A-frags; GEMM2 = w @ fv ----------
    floatx4 acc2[4] = {};                      // 16 pts x 64 fdim, 4 n-tiles of 16
    float lsum = 0.f;
    for (int c = 0; c < NCHUNK; ++c) {
        const floatx4* lp = lp4 + c*32 + quad*8;
        const bool valid = (c < NCHUNK-1) || (quad == 0);
        union { short8 v; unsigned short u[8]; } af;
        #pragma unroll
        for (int j = 0; j < 8; ++j) {
            floatx4 L = lp[j];
            float dx = x0 - L[0], dy = x1 - L[1], dz = x2 - L[2];
            float d2 = fmaf(dx, dx, fmaf(dy, dy, dz*dz));
            d2 = fmaxf(d2, 1e-24f);
            float rs = __builtin_amdgcn_rsqf(d2);
            float inv = __builtin_amdgcn_rcpf(fmaf(d2, rs, 1e-6f));
            float p = valid ? __expf(inv - m) : 0.f;
            unsigned short pb = f2bf(p);
            af.u[j] = pb;
            lsum += bf2f(pb);                 // keep denominator consistent w/ bf16 numerator
        }
        const short8* bp = (const short8*)fvB + (c*4 + quad)*64;
        #pragma unroll
        for (int nt = 0; nt < 4; ++nt) {
            short8 b = bp[nt*16 + ptl];
            acc2[nt] = __builtin_amdgcn_mfma_f32_16x16x32_bf16(af.v, b, acc2[nt], 0, 0, 0);
        }
    }
    lsum += __shfl_xor(lsum, 16);
    lsum += __shfl_xor(lsum, 32);
    const float linv = __builtin_amdgcn_rcpf(lsum);

    // ---------- stage y = [PE(36) | feats(64) | zeros(pad to 128)] into LDS (bf16) ----------
    const int myrow = (wv*16 + ptl) * 136;
    // zero cols 96..127 (layer-0 K padding; feats will overwrite 96..99)
    *(short8*)&act[myrow + 96 + quad*8] = (short8)0;

    // PE: lane computes 9 of the 36 terms for its pt
    #pragma unroll
    for (int i = 0; i < 9; ++i) {
        int k = quad*9 + i;
        int d = k / 12, r12 = k % 12, l = r12 % 6;
        float xv = (d == 0) ? x0 : (d == 1) ? x1 : x2;
        float ang = xv * (PI_F * (float)(1 << l));
        float v = (r12 < 6) ? __sinf(ang) : __cosf(ang);
        act[myrow + k] = f2bf(v);
    }

    // feats (C-layout): row = quad*4+r, col = nt*16+ptl; normalize by lsum
    float linv_r[4];
    #pragma unroll
    for (int r = 0; r < 4; ++r) linv_r[r] = __shfl(linv, quad*4 + r);
    #pragma unroll
    for (int nt = 0; nt < 4; ++nt)
        #pragma unroll
        for (int r = 0; r < 4; ++r)
            act[(wv*16 + quad*4 + r)*136 + 36 + nt*16 + ptl] = f2bf(acc2[nt][r] * linv_r[r]);

    // ---------- MLP layers 0..3: [16 x 128] = [16 x 128] @ W^T via MFMA ----------
    for (int Lyr = 0; Lyr < 4; ++Lyr) {
        const short8* WBp = (const short8*)(WB + Lyr*16384);
        const float* bL = (Lyr == 0) ? b0 : (Lyr == 1) ? b1 : (Lyr == 2) ? b2 : b3;

        short8 a[4];
        #pragma unroll
        for (int c = 0; c < 4; ++c)
            a[c] = *(const short8*)&act[myrow + c*32 + quad*8];

        floatx4 acc[8] = {};
        #pragma unroll
        for (int nt = 0; nt < 8; ++nt) {
            #pragma unroll
            for (int c = 0; c < 4; ++c) {
                short8 b = WBp[(c*4 + quad)*128 + nt*16 + ptl];
                acc[nt] = __builtin_amdgcn_mfma_f32_16x16x32_bf16(a[c], b, acc[nt], 0, 0, 0);
            }
        }
        #pragma unroll
        for (int nt = 0; nt < 8; ++nt) {
            float bias = bL[nt*16 + ptl];
            #pragma unroll
            for (int r = 0; r < 4; ++r) {
                float h = acc[nt][r] + bias;
                float s = __sinf(h);
                h = 0.5f*h + s*s;                       // SnakeAlt
                act[(wv*16 + quad*4 + r)*136 + nt*16 + ptl] = f2bf(h);
            }
        }
    }

    // ---------- layer 4: 128 -> 1 (vector dot + wave reduce) ----------
    float o = 0.f;
    #pragma unroll
    for (int s = 0; s < 4; ++s) {
        short8 av = *(const short8*)&act[myrow + quad*32 + s*8];
        const floatx4* wp = (const floatx4*)W4 + (quad*32 + s*8)/4;
        floatx4 w0 = wp[0], w1 = wp[1];
        o = fmaf(bf2f((unsigned short)av[0]), w0[0], o);
        o = fmaf(bf2f((unsigned short)av[1]), w0[1], o);
        o = fmaf(bf2f((unsigned short)av[2]), w0[2], o);
        o = fmaf(bf2f((unsigned short)av[3]), w0[3], o);
        o = fmaf(bf2f((unsigned short)av[4]), w1[0], o);
        o = fmaf(bf2f((unsigned short)av[5]), w1[1], o);
        o = fmaf(bf2f((unsigned short)av[6]), w1[2], o);
        o = fmaf(bf2f((unsigned short)av[7]), w1[3], o);
    }
    o += __shfl_xor(o, 16);
    o += __shfl_xor(o, 32);
    if (quad == 0) out[ptbase + ptl] = o + b4[0];
}

extern "C" void kernel_launch(void* const* d_in, const int* in_sizes, int n_in,
                              void* d_out, int out_size, void* d_ws, size_t ws_size,
                              hipStream_t stream)
{
    const float* x  = (const float*)d_in[0];
    const float* lc = (const float*)d_in[1];
    const float* fv = (const float*)d_in[2];
    const float* W0 = (const float*)d_in[3];
    const float* b0 = (const float*)d_in[4];
    const float* W1 = (const float*)d_in[5];
    const float* b1 = (const float*)d_in[6];
    const float* W2 = (const float*)d_in[7];
    const float* b2 = (const float*)d_in[8];
    const float* W3 = (const float*)d_in[9];
    const float* b3 = (const float*)d_in[10];
    const float* W4 = (const float*)d_in[11];
    const float* b4 = (const float*)d_in[12];

    char* ws = (char*)d_ws;
    float*          locs4 = (float*)ws;                              // 16 KB
    unsigned short* fvB   = (unsigned short*)(ws + 16384);           // 128 KB
    unsigned short* WB    = (unsigned short*)(ws + 16384 + 131072);  // 128 KB

    prep_locs4<<<dim3(4),   dim3(256), 0, stream>>>(lc, locs4);
    prep_fvB  <<<dim3(256), dim3(256), 0, stream>>>(fv, fvB);
    prep_WB   <<<dim3(256), dim3(256), 0, stream>>>(W0, W1, W2, W3, WB);

    afvsrn_mfma<<<dim3(N_PTS/64), dim3(256), 0, stream>>>(
        x, locs4, fvB, WB, b0, b1, b2, b3, W4, b4, (float*)d_out);
}

// Round 3
// 235.673 us; speedup vs baseline: 4.4628x; 1.1891x over previous
//
#include <hip/hip_runtime.h>
#include <hip/hip_bf16.h>

#define N_PTS   131072
#define N_FEATS 1000
#define FDIM    64
#define HID     128
#define NCHUNK  32          // 32 K-chunks of 32 features (padded 1000 -> 1024)
#define PI_F    3.14159265358979f

typedef short  short8  __attribute__((ext_vector_type(8)));   // bf16 A/B frag (4 VGPRs)
typedef float  floatx4 __attribute__((ext_vector_type(4)));   // C/D frag
typedef float  f4      __attribute__((ext_vector_type(4)));

// ---- bf16 helpers ----
__device__ __forceinline__ unsigned short f2bf(float f) {     // RNE (prep only)
    unsigned int u = __float_as_uint(f);
    u = (u + 0x7FFFu + ((u >> 16) & 1u)) >> 16;
    return (unsigned short)u;
}
__device__ __forceinline__ float bf2f(unsigned short h) {
    return __uint_as_float(((unsigned int)h) << 16);
}
__device__ __forceinline__ unsigned int packbf2(float a, float b) {
    float2 t; t.x = a; t.y = b;
    __hip_bfloat162 h = __float22bfloat162_rn(t);
    union { __hip_bfloat162 hh; unsigned int u; } cv; cv.hh = h;
    return cv.u;
}
__device__ __forceinline__ f4 min4(f4 a, f4 b) {
    f4 r;
    r[0] = fminf(a[0], b[0]); r[1] = fminf(a[1], b[1]);
    r[2] = fminf(a[2], b[2]); r[3] = fminf(a[3], b[3]);
    return r;
}

// ---------------- fused prep: SoA locs + bf16 fragment-ordered fv / W ----------------
// i in [0,65536): fvB   [cq=chunk*4+quad][n=0..63][j=0..7]
// i in [65536,131072): WB (4 layers)  [cq][n=0..127][j=0..7], layer0 K padded 100->128
// i in [131072,132096): LX/LY/LZ [1024], pads at 1e9 (never the min distance)
__global__ void prep_all(const float* __restrict__ locs, const float* __restrict__ fv,
                         const float* __restrict__ W0, const float* __restrict__ W1,
                         const float* __restrict__ W2, const float* __restrict__ W3,
                         float* __restrict__ LX, float* __restrict__ LY, float* __restrict__ LZ,
                         unsigned short* __restrict__ fvB, unsigned short* __restrict__ WB)
{
    int i = blockIdx.x * 256 + threadIdx.x;
    if (i < 65536) {
        int j = i & 7, n = (i >> 3) & 63, cq = i >> 9;
        int f = (cq >> 2) * 32 + (cq & 3) * 8 + j;
        float v = (f < N_FEATS) ? fv[f*FDIM + n] : 0.f;
        fvB[i] = f2bf(v);
    } else if (i < 131072) {
        int r = i - 65536;
        int L = r >> 14, rr = r & 16383;
        int j = rr & 7, n = (rr >> 3) & 127, cq = rr >> 10;
        int k = (cq >> 2) * 32 + (cq & 3) * 8 + j;
        const float* W = (L == 0) ? W0 : (L == 1) ? W1 : (L == 2) ? W2 : W3;
        int Kin = (L == 0) ? 100 : 128;
        float v = (k < Kin) ? W[n*Kin + k] : 0.f;
        WB[r] = f2bf(v);
    } else if (i < 132096) {
        int t = i - 131072;
        bool val = t < N_FEATS;
        LX[t] = val ? locs[t*3+0] : 1e9f;
        LY[t] = val ? locs[t*3+1] : 1e9f;
        LZ[t] = val ? locs[t*3+2] : 1e9f;
    }
}

// ---------------- main fused kernel ----------------
// 4 waves/block, 16 points/wave, no __syncthreads (act rows are wave-private).
__global__ __launch_bounds__(256, 4)
void afvsrn_mfma(const float* __restrict__ x,
                 const float* __restrict__ LX, const float* __restrict__ LY,
                 const float* __restrict__ LZ,
                 const unsigned short* __restrict__ fvB,
                 const unsigned short* __restrict__ WB,
                 const float* __restrict__ b0, const float* __restrict__ b1,
                 const float* __restrict__ b2, const float* __restrict__ b3,
                 const float* __restrict__ W4, const float* __restrict__ b4,
                 float* __restrict__ out)
{
    __shared__ unsigned short act[64 * 136];   // [64 pts][128 + 8 pad] bf16

    const int lane = threadIdx.x & 63;
    const int wv   = threadIdx.x >> 6;
    const int ptl  = lane & 15;                // A-frag row m / C-frag col n
    const int quad = lane >> 4;                // A/B-frag k-group, C-frag row-group
    const int ptbase = blockIdx.x * 64 + wv * 16;

    const float x0 = x[(ptbase + ptl)*3 + 0];
    const float x1 = x[(ptbase + ptl)*3 + 1];
    const float x2 = x[(ptbase + ptl)*3 + 2];

    const f4* LX4 = (const f4*)LX;
    const f4* LY4 = (const f4*)LY;
    const f4* LZ4 = (const f4*)LZ;

    // ---------- pass 1: min d2 only (no transcendentals) ----------
    f4 mn = {1e30f, 1e30f, 1e30f, 1e30f};
    #pragma unroll 2
    for (int c = 0; c < NCHUNK; ++c) {
        int g = c*8 + quad*2;
        f4 lx0 = LX4[g], lx1 = LX4[g+1];
        f4 ly0 = LY4[g], ly1 = LY4[g+1];
        f4 lz0 = LZ4[g], lz1 = LZ4[g+1];
        f4 dx0 = x0 - lx0, dy0 = x1 - ly0, dz0 = x2 - lz0;
        f4 dx1 = x0 - lx1, dy1 = x1 - ly1, dz1 = x2 - lz1;
        f4 d20 = dx0*dx0; d20 += dy0*dy0; d20 += dz0*dz0;
        f4 d21 = dx1*dx1; d21 += dy1*dy1; d21 += dz1*dz1;
        mn = min4(mn, d20);
        mn = min4(mn, d21);
    }
    float md = fminf(fminf(mn[0], mn[1]), fminf(mn[2], mn[3]));
    md = fminf(md, __shfl_xor(md, 16));
    md = fminf(md, __shfl_xor(md, 32));
    // m = max inv_d = rsqrt(min d2); same rsq as pass 2 -> inv-m <= ~0 always
    const float m = __builtin_amdgcn_rsqf(fmaxf(md, 1e-12f));

    // ---------- pass 2: p = exp(inv-m) into A-frags; GEMM feats = w @ fv ----------
    floatx4 acc2[4] = {};
    f4 ls = {0.f, 0.f, 0.f, 0.f};
    #pragma unroll 2
    for (int c = 0; c < NCHUNK; ++c) {
        int g = c*8 + quad*2;
        f4 lx0 = LX4[g], lx1 = LX4[g+1];
        f4 ly0 = LY4[g], ly1 = LY4[g+1];
        f4 lz0 = LZ4[g], lz1 = LZ4[g+1];
        f4 dx0 = x0 - lx0, dy0 = x1 - ly0, dz0 = x2 - lz0;
        f4 dx1 = x0 - lx1, dy1 = x1 - ly1, dz1 = x2 - lz1;
        f4 d20 = dx0*dx0; d20 += dy0*dy0; d20 += dz0*dz0;
        f4 d21 = dx1*dx1; d21 += dy1*dy1; d21 += dz1*dz1;
        // last chunk: features 992..1023, only quad 0 (992..999) is real.
        // m' = 3e38 makes exp underflow to exactly 0 for the pad lanes.
        const float mq = ((c == NCHUNK-1) && (quad != 0)) ? 3e38f : m;
        f4 p0, p1;
        #pragma unroll
        for (int e = 0; e < 4; ++e) {
            p0[e] = __expf(__builtin_amdgcn_rsqf(fmaxf(d20[e], 1e-12f)) - mq);
            p1[e] = __expf(__builtin_amdgcn_rsqf(fmaxf(d21[e], 1e-12f)) - mq);
        }
        ls += p0; ls += p1;
        union { short8 v; unsigned int u[4]; } af;
        af.u[0] = packbf2(p0[0], p0[1]);
        af.u[1] = packbf2(p0[2], p0[3]);
        af.u[2] = packbf2(p1[0], p1[1]);
        af.u[3] = packbf2(p1[2], p1[3]);
        const short8* bp = (const short8*)fvB + (c*4 + quad)*64;
        #pragma unroll
        for (int nt = 0; nt < 4; ++nt) {
            short8 b = bp[nt*16 + ptl];
            acc2[nt] = __builtin_amdgcn_mfma_f32_16x16x32_bf16(af.v, b, acc2[nt], 0, 0, 0);
        }
    }
    float lsum = (ls[0] + ls[1]) + (ls[2] + ls[3]);
    lsum += __shfl_xor(lsum, 16);
    lsum += __shfl_xor(lsum, 32);
    const float linv = __builtin_amdgcn_rcpf(lsum);

    // ---------- stage y = [PE(36) | feats(64) | zero pad to 128] ----------
    const int myrow = (wv*16 + ptl) * 136;
    *(short8*)&act[myrow + 96 + quad*8] = (short8)0;

    #pragma unroll
    for (int i = 0; i < 9; ++i) {
        int k = quad*9 + i;
        int d = k / 12, r12 = k % 12, l = r12 % 6;
        float xv = (d == 0) ? x0 : (d == 1) ? x1 : x2;
        float ang = xv * (PI_F * (float)(1 << l));
        float v = (r12 < 6) ? __sinf(ang) : __cosf(ang);
        act[myrow + k] = f2bf(v);
    }

    float linv_r[4];
    #pragma unroll
    for (int r = 0; r < 4; ++r) linv_r[r] = __shfl(linv, quad*4 + r);
    #pragma unroll
    for (int nt = 0; nt < 4; ++nt)
        #pragma unroll
        for (int r = 0; r < 4; ++r)
            act[(wv*16 + quad*4 + r)*136 + 36 + nt*16 + ptl] = f2bf(acc2[nt][r] * linv_r[r]);

    // ---------- MLP layers 0..3 via MFMA ----------
    for (int Lyr = 0; Lyr < 4; ++Lyr) {
        const short8* WBp = (const short8*)(WB + Lyr*16384);
        const float* bL = (Lyr == 0) ? b0 : (Lyr == 1) ? b1 : (Lyr == 2) ? b2 : b3;

        short8 a[4];
        #pragma unroll
        for (int c = 0; c < 4; ++c)
            a[c] = *(const short8*)&act[myrow + c*32 + quad*8];

        floatx4 acc[8] = {};
        #pragma unroll
        for (int nt = 0; nt < 8; ++nt) {
            #pragma unroll
            for (int c = 0; c < 4; ++c) {
                short8 b = WBp[(c*4 + quad)*128 + nt*16 + ptl];
                acc[nt] = __builtin_amdgcn_mfma_f32_16x16x32_bf16(a[c], b, acc[nt], 0, 0, 0);
            }
        }
        #pragma unroll
        for (int nt = 0; nt < 8; ++nt) {
            float bias = bL[nt*16 + ptl];
            #pragma unroll
            for (int r = 0; r < 4; ++r) {
                float h = acc[nt][r] + bias;
                float s = __sinf(h);
                h = 0.5f*h + s*s;                       // SnakeAlt
                act[(wv*16 + quad*4 + r)*136 + nt*16 + ptl] = f2bf(h);
            }
        }
    }

    // ---------- layer 4: 128 -> 1 ----------
    float o = 0.f;
    #pragma unroll
    for (int s = 0; s < 4; ++s) {
        short8 av = *(const short8*)&act[myrow + quad*32 + s*8];
        const floatx4* wp = (const floatx4*)W4 + (quad*32 + s*8)/4;
        floatx4 w0 = wp[0], w1 = wp[1];
        o = fmaf(bf2f((unsigned short)av[0]), w0[0], o);
        o = fmaf(bf2f((unsigned short)av[1]), w0[1], o);
        o = fmaf(bf2f((unsigned short)av[2]), w0[2], o);
        o = fmaf(bf2f((unsigned short)av[3]), w0[3], o);
        o = fmaf(bf2f((unsigned short)av[4]), w1[0], o);
        o = fmaf(bf2f((unsigned short)av[5]), w1[1], o);
        o = fmaf(bf2f((unsigned short)av[6]), w1[2], o);
        o = fmaf(bf2f((unsigned short)av[7]), w1[3], o);
    }
    o += __shfl_xor(o, 16);
    o += __shfl_xor(o, 32);
    if (quad == 0) out[ptbase + ptl] = o + b4[0];
}

extern "C" void kernel_launch(void* const* d_in, const int* in_sizes, int n_in,
                              void* d_out, int out_size, void* d_ws, size_t ws_size,
                              hipStream_t stream)
{
    const float* x  = (const float*)d_in[0];
    const float* lc = (const float*)d_in[1];
    const float* fv = (const float*)d_in[2];
    const float* W0 = (const float*)d_in[3];
    const float* b0 = (const float*)d_in[4];
    const float* W1 = (const float*)d_in[5];
    const float* b1 = (const float*)d_in[6];
    const float* W2 = (const float*)d_in[7];
    const float* b2 = (const float*)d_in[8];
    const float* W3 = (const float*)d_in[9];
    const float* b3 = (const float*)d_in[10];
    const float* W4 = (const float*)d_in[11];
    const float* b4 = (const float*)d_in[12];

    char* ws = (char*)d_ws;
    float*          LXp = (float*)(ws + 0);
    float*          LYp = (float*)(ws + 4096);
    float*          LZp = (float*)(ws + 8192);
    unsigned short* fvB = (unsigned short*)(ws + 16384);            // 128 KB
    unsigned short* WB  = (unsigned short*)(ws + 16384 + 131072);   // 128 KB

    prep_all<<<dim3(516), dim3(256), 0, stream>>>(lc, fv, W0, W1, W2, W3,
                                                  LXp, LYp, LZp, fvB, WB);

    afvsrn_mfma<<<dim3(N_PTS/64), dim3(256), 0, stream>>>(
        x, LXp, LYp, LZp, fvB, WB, b0, b1, b2, b3, W4, b4, (float*)d_out);
}